// Round 16
// baseline (158.401 us; speedup 1.0000x reference)
//
#include <hip/hip_runtime.h>

#define BB 4096
#define TT 256
#define FF 32
#define HH 6

#define DPP_XOR1 0xB1   // quad_perm(1,0,3,2)
#define DPP_XOR2 0x4E   // quad_perm(2,3,0,1)
#define DPP_XOR3 0x1B   // quad_perm(3,2,1,0)
#define DPP_HALF 0x141  // row_half_mirror = xor 7 within 8-lane half-rows

__device__ __forceinline__ float fast_rcp(float x) { return __builtin_amdgcn_rcpf(x); }
__device__ __forceinline__ float sigmoidf(float x) { return fast_rcp(1.0f + __expf(-x)); }

template <int CTRL>
__device__ __forceinline__ float dppf(float x) {
    return __int_as_float(__builtin_amdgcn_update_dpp(
        0, __float_as_int(x), CTRL, 0xF, 0xF, true));
}
__device__ __forceinline__ float dpp_xor4(float x) {
    return dppf<DPP_HALF>(dppf<DPP_XOR3>(x));
}

typedef const __attribute__((address_space(1))) void* gas_ptr;
typedef __attribute__((address_space(3))) void* las_ptr;
__device__ __forceinline__ void gl_lds16(const float* g, float* l) {
    __builtin_amdgcn_global_load_lds((gas_ptr)g, (las_ptr)l, 16, 0, 0);
}

// K1 (verbatim R13/R15, verified): 4 lanes per (b,t) item, interleaved ownership.
__global__ __launch_bounds__(256, 4) void k_attn_xz(
    const float* __restrict__ x, const float* __restrict__ Wa, const float* __restrict__ ba,
    const float* __restrict__ Wl, const float* __restrict__ bl, float* __restrict__ xz)
{
    __shared__ __align__(16) float wa_s[FF * 36];   // rows padded 32->36 floats
    __shared__ __align__(16) float wl_s[FF * 28];   // rows padded 24->28 floats
    const int lt = threadIdx.x;

    {
        const float4 v = *(const float4*)(Wa + lt * 4);
        *(float4*)(wa_s + (lt >> 3) * 36 + (lt & 7) * 4) = v;
        if (lt < 192) {
            const float4 w = *(const float4*)(Wl + lt * 4);
            *(float4*)(wl_s + (lt / 6) * 28 + (lt % 6) * 4) = w;
        }
    }
    __syncthreads();

    const int tid = blockIdx.x * 256 + threadIdx.x;
    const int item = tid >> 2;
    const int q = tid & 3;
    const bool b0 = (q & 1) != 0;
    const bool b1 = (q & 2) != 0;
    const float* xp = x + (size_t)item * FF;

    float own[8];
#pragma unroll
    for (int i = 0; i < 8; ++i) own[i] = xp[4 * i + q];

    float partial[32];
#pragma unroll
    for (int c = 0; c < 32; ++c) partial[c] = 0.0f;

#define PHA(I) { \
        const float xi = own[I]; \
        const float* wr = wa_s + (4 * (I) + q) * 36; \
        _Pragma("unroll") \
        for (int cc = 0; cc < 8; ++cc) { \
            const float4 w = *(const float4*)(wr + cc * 4); \
            partial[cc*4+0] = fmaf(xi, w.x, partial[cc*4+0]); \
            partial[cc*4+1] = fmaf(xi, w.y, partial[cc*4+1]); \
            partial[cc*4+2] = fmaf(xi, w.z, partial[cc*4+2]); \
            partial[cc*4+3] = fmaf(xi, w.w, partial[cc*4+3]); \
        } }
    PHA(0) PHA(1) PHA(2) PHA(3) PHA(4) PHA(5) PHA(6) PHA(7)
#undef PHA

    float dotv[8];
#define RSG(CI) { \
        const float p0 = partial[4*(CI)+0], p1 = partial[4*(CI)+1]; \
        const float p2 = partial[4*(CI)+2], p3 = partial[4*(CI)+3]; \
        const float v01 = b0 ? p1 : p0, u01 = b0 ? p0 : p1; \
        const float v23 = b0 ? p3 : p2, u23 = b0 ? p2 : p3; \
        const float r01 = v01 + dppf<DPP_XOR1>(u01); \
        const float r23 = v23 + dppf<DPP_XOR1>(u23); \
        const float vv = b1 ? r23 : r01, uu = b1 ? r01 : r23; \
        dotv[CI] = vv + dppf<DPP_XOR2>(uu); }
    RSG(0) RSG(1) RSG(2) RSG(3) RSG(4) RSG(5) RSG(6) RSG(7)
#undef RSG

    float e[8];
    float sum = 0.0f;
#pragma unroll
    for (int i = 0; i < 8; ++i) {
        e[i] = __expf(dotv[i] + ba[4 * i + q]);
        sum += e[i];
    }
    sum += dppf<DPP_XOR1>(sum);
    sum += dppf<DPP_XOR2>(sum);

    float acc[24];
#pragma unroll
    for (int g = 0; g < 24; ++g) acc[g] = 0.0f;

#define PHB(I) { \
        const float pp = own[I] * e[I]; \
        const float* wr = wl_s + (4 * (I) + q) * 28; \
        _Pragma("unroll") \
        for (int gc = 0; gc < 6; ++gc) { \
            const float4 w = *(const float4*)(wr + gc * 4); \
            acc[gc*4+0] = fmaf(pp, w.x, acc[gc*4+0]); \
            acc[gc*4+1] = fmaf(pp, w.y, acc[gc*4+1]); \
            acc[gc*4+2] = fmaf(pp, w.z, acc[gc*4+2]); \
            acc[gc*4+3] = fmaf(pp, w.w, acc[gc*4+3]); \
        } }
    PHB(0) PHB(1) PHB(2) PHB(3) PHB(4) PHB(5) PHB(6) PHB(7)
#undef PHB

#pragma unroll
    for (int g = 0; g < 24; ++g) acc[g] += dppf<DPP_XOR1>(acc[g]);
#pragma unroll
    for (int g = 0; g < 24; ++g) acc[g] += dppf<DPP_XOR2>(acc[g]);

    const float r = fast_rcp(sum);

    float* op = xz + (size_t)item * 24;
    {
        const float ai = (q == 0) ? acc[0]  : (q == 1) ? acc[1]  : (q == 2) ? acc[2]  : acc[3];
        const float af = (q == 0) ? acc[6]  : (q == 1) ? acc[7]  : (q == 2) ? acc[8]  : acc[9];
        const float ag = (q == 0) ? acc[12] : (q == 1) ? acc[13] : (q == 2) ? acc[14] : acc[15];
        const float ao = (q == 0) ? acc[18] : (q == 1) ? acc[19] : (q == 2) ? acc[20] : acc[21];
        float4 o;
        o.x = fmaf(ai, r, bl[0  + q]);
        o.y = fmaf(af, r, bl[6  + q]);
        o.z = fmaf(ag, r, bl[12 + q]);
        o.w = fmaf(ao, r, bl[18 + q]);
        *(float4*)(op + q * 4) = o;
    }
    if (q < 2) {
        const int jp = 4 + q;
        const float ai = (q == 0) ? acc[4]  : acc[5];
        const float af = (q == 0) ? acc[10] : acc[11];
        const float ag = (q == 0) ? acc[16] : acc[17];
        const float ao = (q == 0) ? acc[22] : acc[23];
        float4 o;
        o.x = fmaf(ai, r, bl[0  + jp]);
        o.y = fmaf(af, r, bl[6  + jp]);
        o.z = fmaf(ag, r, bl[12 + jp]);
        o.w = fmaf(ao, r, bl[18 + jp]);
        *(float4*)(op + jp * 4) = o;
    }
}

// One LSTM step (defer-max c-softmax, verified). Returns hn.
__device__ __forceinline__ float chain_step(
    float hl[8], float& c, float& r2,
    const float Ui[8], const float Uf[8], const float Ug[8], const float Uo[8],
    const float4 z4, const bool real)
{
    float di0 = hl[0]*Ui[0], di1 = hl[4]*Ui[4];
    float df0 = hl[0]*Uf[0], df1 = hl[4]*Uf[4];
    float dg0 = hl[0]*Ug[0], dg1 = hl[4]*Ug[4];
    float dq0 = hl[0]*Uo[0], dq1 = hl[4]*Uo[4];
#pragma unroll
    for (int m = 1; m < 4; ++m) {
        di0 = fmaf(hl[m], Ui[m], di0); di1 = fmaf(hl[m+4], Ui[m+4], di1);
        df0 = fmaf(hl[m], Uf[m], df0); df1 = fmaf(hl[m+4], Uf[m+4], df1);
        dg0 = fmaf(hl[m], Ug[m], dg0); dg1 = fmaf(hl[m+4], Ug[m+4], dg1);
        dq0 = fmaf(hl[m], Uo[m], dq0); dq1 = fmaf(hl[m+4], Uo[m+4], dq1);
    }
    const float zi = fmaf(di0 + di1, r2, z4.x);
    const float zf = fmaf(df0 + df1, r2, z4.y);
    const float zg = fmaf(dg0 + dg1, r2, z4.z);
    const float zo = fmaf(dq0 + dq1, r2, z4.w);

    const float iv = sigmoidf(zi);
    const float fv = sigmoidf(zf);
    const float ov = sigmoidf(zo);

    const float eg = real ? __expf(zg) : 0.0f;
    float s1 = eg;
    s1 += dppf<DPP_XOR1>(s1);
    s1 += dppf<DPP_XOR2>(s1);
    s1 += dpp_xor4(s1);
    c = fmaf(fv, c, (iv * eg) * fast_rcp(s1));

    const float ec = real ? __expf(c) : 0.0f;   // defer-max (uniform exp(-m) cancels)
    float s2 = ec;
    s2 += dppf<DPP_XOR1>(s2);
    s2 += dppf<DPP_XOR2>(s2);
    s2 += dpp_xor4(s2);

    const float ovec = ov * ec;
    hl[0] = ovec;
    hl[1] = dppf<DPP_XOR1>(ovec);
    hl[2] = dppf<DPP_XOR2>(ovec);
    hl[3] = dppf<DPP_XOR3>(ovec);
    const float h7 = dppf<DPP_HALF>(ovec);
    hl[7] = h7;
    hl[6] = dppf<DPP_XOR1>(h7);
    hl[5] = dppf<DPP_XOR2>(h7);
    hl[4] = dppf<DPP_XOR3>(h7);
    r2 = fast_rcp(s2);
    return ovec * r2;
}

// K2 v5: LDS ring staging (as R15) + 2-step-ahead register rotation for BOTH
// the z float4 (zcur/zn1/zn2) and the W10 row (wr0/wr1) — every LDS read is
// issued ~2 steps (~1900 cy) before its use. Ring residency race at gi=30
// fixed with a one-time vmcnt(0).
__global__ __launch_bounds__(64, 1) void k_scan(
    const float* __restrict__ xz, const float* __restrict__ Ul,
    const float* __restrict__ W10, const float* __restrict__ b10,
    const float* __restrict__ Wo, const float* __restrict__ bo,
    float* __restrict__ out)
{
    const int lane = threadIdx.x;
    const int j = lane & 7;
    const int b = blockIdx.x * 8 + (lane >> 3);
    const bool real = (j < HH);
    const int jc = real ? j : 0;

    __shared__ __align__(16) float w10s[TT * HH * 10 + 128];  // +2 junk rows (t=256,257)
    __shared__ __align__(1024) float ring[16 * 256];           // 16 steps x 1KB

    {
        const float2* src = (const float2*)W10;
        float2* dst = (float2*)w10s;
        for (int i = lane; i < (TT * HH * 10) / 2; i += 64) dst[i] = src[i];
        // zero the 2 junk rows so junk reads are defined
        for (int i = lane; i < 64; i += 64) {
            dst[(TT * HH * 10) / 2 + i] = make_float2(0.f, 0.f);
        }
    }
    __syncthreads();

    float Ui[8], Uf[8], Ug[8], Uo[8];
#pragma unroll
    for (int m = 0; m < 8; ++m) {
        const int src = j ^ m;
        const bool ok = real && (src < HH);
        const float* row = Ul + (ok ? src : 0) * 24;
        Ui[m] = ok ? row[0  + j] : 0.0f;
        Uf[m] = ok ? row[6  + j] : 0.0f;
        Ug[m] = ok ? row[12 + j] : 0.0f;
        Uo[m] = ok ? row[18 + j] : 0.0f;
    }

    float hl[8];
    float r2 = 1.0f, c = 0.0f;
    float y[10];
#pragma unroll
    for (int m = 0; m < 8; ++m) hl[m] = 0.0f;
#pragma unroll
    for (int p = 0; p < 10; ++p) y[p] = 0.0f;

    const float* gsrc = xz + (size_t)b * (TT * 24) + j * 4;

#define STAGE(G) { \
        const float* s_ = gsrc + (size_t)((G) * 8) * 24; \
        float* lb_ = ring + (((G) * 8) & 15) * 256; \
        _Pragma("unroll") \
        for (int k_ = 0; k_ < 8; ++k_) gl_lds16(s_ + k_ * 24, lb_ + k_ * 256); }

    STAGE(0) STAGE(1)
    asm volatile("s_waitcnt vmcnt(8)" ::: "memory");   // group 0 resident

    // z rotation: zcur(t), zn1(t+1); zn2 loaded per step for t+2
    float4 zcur = *(const float4*)(ring + 0 * 256 + lane * 4);
    float4 zn1  = *(const float4*)(ring + 1 * 256 + lane * 4);
    // W10 rotation: wr0 = row(t), wr1 = row(t+1)
    float2 wr0[5], wr1[5];
#pragma unroll
    for (int q = 0; q < 5; ++q) {
        wr0[q] = *(const float2*)(w10s + (0 * HH + jc) * 10 + q * 2);
        wr1[q] = *(const float2*)(w10s + (1 * HH + jc) * 10 + q * 2);
    }

    // One step: issue reads for t+2 (z and W10 row), run chain, consume wr0, rotate.
#define STEP(K) { \
        const int t_ = t0 + (K); \
        const float4 zn2 = *(const float4*)(ring + (((sb + (K) + 2) & 15) << 8) + lane * 4); \
        float2 wn[5]; \
        const int rn_ = ((t_ + 2) * HH + jc) * 10; \
        _Pragma("unroll") \
        for (int q_ = 0; q_ < 5; ++q_) wn[q_] = *(const float2*)(w10s + rn_ + q_ * 2); \
        const float hn = chain_step(hl, c, r2, Ui, Uf, Ug, Uo, zcur, real); \
        _Pragma("unroll") \
        for (int q_ = 0; q_ < 5; ++q_) { \
            y[2*q_]   = fmaf(hn, wr0[q_].x, y[2*q_]); \
            y[2*q_+1] = fmaf(hn, wr0[q_].y, y[2*q_+1]); \
        } \
        _Pragma("unroll") \
        for (int q_ = 0; q_ < 5; ++q_) { wr0[q_] = wr1[q_]; wr1[q_] = wn[q_]; } \
        zcur = zn1; zn1 = zn2; }

#pragma unroll 1
    for (int gi = 0; gi < 32; ++gi) {
        const int t0 = gi * 8;
        const int sb = (gi & 1) * 8;
        // k=0..5: reads reach at most t0+7 (this group, resident)
        STEP(0) STEP(1) STEP(2) STEP(3) STEP(4) STEP(5)
        // boundary: restage consumed slots, then guarantee group gi+1 resident
        if (gi < 30) {
            STAGE(gi + 2)
            asm volatile("s_waitcnt vmcnt(8)" ::: "memory");
        } else if (gi == 30) {
            asm volatile("s_waitcnt vmcnt(0)" ::: "memory");   // force group 31 resident
        }
        // k=6,7: reads reach t0+8, t0+9 (group gi+1; for gi=31 reads junk slot, unused)
        STEP(6) STEP(7)
    }
#undef STEP
#undef STAGE

    // reduce y across the 8-lane group
#pragma unroll
    for (int p = 0; p < 10; ++p) {
        float v = y[p];
        v += dppf<DPP_XOR1>(v);
        v += dppf<DPP_XOR2>(v);
        v += dpp_xor4(v);
        y[p] = v;
    }

    float o8 = bo[j];
#pragma unroll
    for (int p = 0; p < 10; ++p) o8 = fmaf(y[p] + b10[p], Wo[p * 8 + j], o8);
    out[(size_t)b * 8 + j] = o8;
}

extern "C" void kernel_launch(void* const* d_in, const int* in_sizes, int n_in,
                              void* d_out, int out_size, void* d_ws, size_t ws_size,
                              hipStream_t stream) {
    const float* x   = (const float*)d_in[0];
    const float* Wa  = (const float*)d_in[1];
    const float* ba  = (const float*)d_in[2];
    const float* Wl  = (const float*)d_in[3];
    const float* Ul  = (const float*)d_in[4];
    const float* bl  = (const float*)d_in[5];
    const float* W10 = (const float*)d_in[6];
    const float* b10 = (const float*)d_in[7];
    const float* Wo  = (const float*)d_in[8];
    const float* bo  = (const float*)d_in[9];
    float* out = (float*)d_out;
    float* xz  = (float*)d_ws;   // BB*TT*24*4 = 96 MiB

    hipLaunchKernelGGL(k_attn_xz, dim3(BB * TT * 4 / 256), dim3(256), 0, stream,
                       x, Wa, ba, Wl, bl, xz);
    hipLaunchKernelGGL(k_scan, dim3(BB / 8), dim3(64), 0, stream,
                       xz, Ul, W10, b10, Wo, bo, out);
}

// Round 17
// 138.504 us; speedup vs baseline: 1.1437x; 1.1437x over previous
//
#include <hip/hip_runtime.h>

#define BB 4096
#define TT 256
#define FF 32
#define HH 6

#define DPP_XOR1 0xB1   // quad_perm(1,0,3,2)
#define DPP_XOR2 0x4E   // quad_perm(2,3,0,1)
#define DPP_XOR3 0x1B   // quad_perm(3,2,1,0)
#define DPP_HALF 0x141  // row_half_mirror = xor 7 within 8-lane half-rows

__device__ __forceinline__ float fast_rcp(float x) { return __builtin_amdgcn_rcpf(x); }
__device__ __forceinline__ float sigmoidf(float x) { return fast_rcp(1.0f + __expf(-x)); }

template <int CTRL>
__device__ __forceinline__ float dppf(float x) {
    return __int_as_float(__builtin_amdgcn_update_dpp(
        0, __float_as_int(x), CTRL, 0xF, 0xF, true));
}
__device__ __forceinline__ float dpp_xor4(float x) {
    return dppf<DPP_HALF>(dppf<DPP_XOR3>(x));
}

typedef const __attribute__((address_space(1))) void* gas_ptr;
typedef __attribute__((address_space(3))) void* las_ptr;
__device__ __forceinline__ void gl_lds16(const float* g, float* l) {
    __builtin_amdgcn_global_load_lds((gas_ptr)g, (las_ptr)l, 16, 0, 0);
}

// K1 (verbatim R13/R15/R16, verified): 4 lanes per (b,t) item, interleaved ownership.
__global__ __launch_bounds__(256, 4) void k_attn_xz(
    const float* __restrict__ x, const float* __restrict__ Wa, const float* __restrict__ ba,
    const float* __restrict__ Wl, const float* __restrict__ bl, float* __restrict__ xz)
{
    __shared__ __align__(16) float wa_s[FF * 36];   // rows padded 32->36 floats
    __shared__ __align__(16) float wl_s[FF * 28];   // rows padded 24->28 floats
    const int lt = threadIdx.x;

    {
        const float4 v = *(const float4*)(Wa + lt * 4);
        *(float4*)(wa_s + (lt >> 3) * 36 + (lt & 7) * 4) = v;
        if (lt < 192) {
            const float4 w = *(const float4*)(Wl + lt * 4);
            *(float4*)(wl_s + (lt / 6) * 28 + (lt % 6) * 4) = w;
        }
    }
    __syncthreads();

    const int tid = blockIdx.x * 256 + threadIdx.x;
    const int item = tid >> 2;
    const int q = tid & 3;
    const bool b0 = (q & 1) != 0;
    const bool b1 = (q & 2) != 0;
    const float* xp = x + (size_t)item * FF;

    float own[8];
#pragma unroll
    for (int i = 0; i < 8; ++i) own[i] = xp[4 * i + q];

    float partial[32];
#pragma unroll
    for (int c = 0; c < 32; ++c) partial[c] = 0.0f;

#define PHA(I) { \
        const float xi = own[I]; \
        const float* wr = wa_s + (4 * (I) + q) * 36; \
        _Pragma("unroll") \
        for (int cc = 0; cc < 8; ++cc) { \
            const float4 w = *(const float4*)(wr + cc * 4); \
            partial[cc*4+0] = fmaf(xi, w.x, partial[cc*4+0]); \
            partial[cc*4+1] = fmaf(xi, w.y, partial[cc*4+1]); \
            partial[cc*4+2] = fmaf(xi, w.z, partial[cc*4+2]); \
            partial[cc*4+3] = fmaf(xi, w.w, partial[cc*4+3]); \
        } }
    PHA(0) PHA(1) PHA(2) PHA(3) PHA(4) PHA(5) PHA(6) PHA(7)
#undef PHA

    float dotv[8];
#define RSG(CI) { \
        const float p0 = partial[4*(CI)+0], p1 = partial[4*(CI)+1]; \
        const float p2 = partial[4*(CI)+2], p3 = partial[4*(CI)+3]; \
        const float v01 = b0 ? p1 : p0, u01 = b0 ? p0 : p1; \
        const float v23 = b0 ? p3 : p2, u23 = b0 ? p2 : p3; \
        const float r01 = v01 + dppf<DPP_XOR1>(u01); \
        const float r23 = v23 + dppf<DPP_XOR1>(u23); \
        const float vv = b1 ? r23 : r01, uu = b1 ? r01 : r23; \
        dotv[CI] = vv + dppf<DPP_XOR2>(uu); }
    RSG(0) RSG(1) RSG(2) RSG(3) RSG(4) RSG(5) RSG(6) RSG(7)
#undef RSG

    float e[8];
    float sum = 0.0f;
#pragma unroll
    for (int i = 0; i < 8; ++i) {
        e[i] = __expf(dotv[i] + ba[4 * i + q]);
        sum += e[i];
    }
    sum += dppf<DPP_XOR1>(sum);
    sum += dppf<DPP_XOR2>(sum);

    float acc[24];
#pragma unroll
    for (int g = 0; g < 24; ++g) acc[g] = 0.0f;

#define PHB(I) { \
        const float pp = own[I] * e[I]; \
        const float* wr = wl_s + (4 * (I) + q) * 28; \
        _Pragma("unroll") \
        for (int gc = 0; gc < 6; ++gc) { \
            const float4 w = *(const float4*)(wr + gc * 4); \
            acc[gc*4+0] = fmaf(pp, w.x, acc[gc*4+0]); \
            acc[gc*4+1] = fmaf(pp, w.y, acc[gc*4+1]); \
            acc[gc*4+2] = fmaf(pp, w.z, acc[gc*4+2]); \
            acc[gc*4+3] = fmaf(pp, w.w, acc[gc*4+3]); \
        } }
    PHB(0) PHB(1) PHB(2) PHB(3) PHB(4) PHB(5) PHB(6) PHB(7)
#undef PHB

#pragma unroll
    for (int g = 0; g < 24; ++g) acc[g] += dppf<DPP_XOR1>(acc[g]);
#pragma unroll
    for (int g = 0; g < 24; ++g) acc[g] += dppf<DPP_XOR2>(acc[g]);

    const float r = fast_rcp(sum);

    float* op = xz + (size_t)item * 24;
    {
        const float ai = (q == 0) ? acc[0]  : (q == 1) ? acc[1]  : (q == 2) ? acc[2]  : acc[3];
        const float af = (q == 0) ? acc[6]  : (q == 1) ? acc[7]  : (q == 2) ? acc[8]  : acc[9];
        const float ag = (q == 0) ? acc[12] : (q == 1) ? acc[13] : (q == 2) ? acc[14] : acc[15];
        const float ao = (q == 0) ? acc[18] : (q == 1) ? acc[19] : (q == 2) ? acc[20] : acc[21];
        float4 o;
        o.x = fmaf(ai, r, bl[0  + q]);
        o.y = fmaf(af, r, bl[6  + q]);
        o.z = fmaf(ag, r, bl[12 + q]);
        o.w = fmaf(ao, r, bl[18 + q]);
        *(float4*)(op + q * 4) = o;
    }
    if (q < 2) {
        const int jp = 4 + q;
        const float ai = (q == 0) ? acc[4]  : acc[5];
        const float af = (q == 0) ? acc[10] : acc[11];
        const float ag = (q == 0) ? acc[16] : acc[17];
        const float ao = (q == 0) ? acc[22] : acc[23];
        float4 o;
        o.x = fmaf(ai, r, bl[0  + jp]);
        o.y = fmaf(af, r, bl[6  + jp]);
        o.z = fmaf(ag, r, bl[12 + jp]);
        o.w = fmaf(ao, r, bl[18 + jp]);
        *(float4*)(op + jp * 4) = o;
    }
}

// One LSTM step (defer-max c-softmax, verified). Returns hn.
__device__ __forceinline__ float chain_step(
    float hl[8], float& c, float& r2,
    const float Ui[8], const float Uf[8], const float Ug[8], const float Uo[8],
    const float4 z4, const bool real)
{
    float di0 = hl[0]*Ui[0], di1 = hl[4]*Ui[4];
    float df0 = hl[0]*Uf[0], df1 = hl[4]*Uf[4];
    float dg0 = hl[0]*Ug[0], dg1 = hl[4]*Ug[4];
    float dq0 = hl[0]*Uo[0], dq1 = hl[4]*Uo[4];
#pragma unroll
    for (int m = 1; m < 4; ++m) {
        di0 = fmaf(hl[m], Ui[m], di0); di1 = fmaf(hl[m+4], Ui[m+4], di1);
        df0 = fmaf(hl[m], Uf[m], df0); df1 = fmaf(hl[m+4], Uf[m+4], df1);
        dg0 = fmaf(hl[m], Ug[m], dg0); dg1 = fmaf(hl[m+4], Ug[m+4], dg1);
        dq0 = fmaf(hl[m], Uo[m], dq0); dq1 = fmaf(hl[m+4], Uo[m+4], dq1);
    }
    const float zi = fmaf(di0 + di1, r2, z4.x);
    const float zf = fmaf(df0 + df1, r2, z4.y);
    const float zg = fmaf(dg0 + dg1, r2, z4.z);
    const float zo = fmaf(dq0 + dq1, r2, z4.w);

    const float iv = sigmoidf(zi);
    const float fv = sigmoidf(zf);
    const float ov = sigmoidf(zo);

    const float eg = real ? __expf(zg) : 0.0f;
    float s1 = eg;
    s1 += dppf<DPP_XOR1>(s1);
    s1 += dppf<DPP_XOR2>(s1);
    s1 += dpp_xor4(s1);
    c = fmaf(fv, c, (iv * eg) * fast_rcp(s1));

    const float ec = real ? __expf(c) : 0.0f;   // defer-max (uniform exp(-m) cancels)
    float s2 = ec;
    s2 += dppf<DPP_XOR1>(s2);
    s2 += dppf<DPP_XOR2>(s2);
    s2 += dpp_xor4(s2);

    const float ovec = ov * ec;
    hl[0] = ovec;
    hl[1] = dppf<DPP_XOR1>(ovec);
    hl[2] = dppf<DPP_XOR2>(ovec);
    hl[3] = dppf<DPP_XOR3>(ovec);
    const float h7 = dppf<DPP_HALF>(ovec);
    hl[7] = h7;
    hl[6] = dppf<DPP_XOR1>(h7);
    hl[5] = dppf<DPP_XOR2>(h7);
    hl[4] = dppf<DPP_XOR3>(h7);
    r2 = fast_rcp(s2);
    return ovec * r2;
}

// K2 v6: deferred-y. Phase 1: pure scan — per step only {1 LDS z-read (2-ahead),
// chain, 1 ds_write hn -> h_lds[256][64]}. NO W10 access in the loop.
// Phase 2: dense(10) as a parallel GEMV — lane (g,j) sums its t-slice
// {t == j mod 8} over all 6 units, h from LDS, W10 rows from global (L2-shared).
__global__ __launch_bounds__(64, 1) void k_scan(
    const float* __restrict__ xz, const float* __restrict__ Ul,
    const float* __restrict__ W10, const float* __restrict__ b10,
    const float* __restrict__ Wo, const float* __restrict__ bo,
    float* __restrict__ out)
{
    const int lane = threadIdx.x;
    const int j = lane & 7;
    const int grp = lane >> 3;
    const int b = blockIdx.x * 8 + grp;
    const bool real = (j < HH);

    __shared__ __align__(1024) float ring[16 * 256];   // 16 steps x 1KB
    __shared__ __align__(16) float h_lds[TT * 64];     // 64KB: h[t][lane]

    float Ui[8], Uf[8], Ug[8], Uo[8];
#pragma unroll
    for (int m = 0; m < 8; ++m) {
        const int src = j ^ m;
        const bool ok = real && (src < HH);
        const float* row = Ul + (ok ? src : 0) * 24;
        Ui[m] = ok ? row[0  + j] : 0.0f;
        Uf[m] = ok ? row[6  + j] : 0.0f;
        Ug[m] = ok ? row[12 + j] : 0.0f;
        Uo[m] = ok ? row[18 + j] : 0.0f;
    }

    float hl[8];
    float r2 = 1.0f, c = 0.0f;
#pragma unroll
    for (int m = 0; m < 8; ++m) hl[m] = 0.0f;

    const float* gsrc = xz + (size_t)b * (TT * 24) + j * 4;

#define STAGE(G) { \
        const float* s_ = gsrc + (size_t)((G) * 8) * 24; \
        float* lb_ = ring + (((G) * 8) & 15) * 256; \
        _Pragma("unroll") \
        for (int k_ = 0; k_ < 8; ++k_) gl_lds16(s_ + k_ * 24, lb_ + k_ * 256); }

    STAGE(0) STAGE(1)
    asm volatile("s_waitcnt vmcnt(8)" ::: "memory");   // group 0 resident

    float4 zcur = *(const float4*)(ring + 0 * 256 + lane * 4);
    float4 zn1  = *(const float4*)(ring + 1 * 256 + lane * 4);

#define STEP(K) { \
        const float4 zn2 = *(const float4*)(ring + (((sb + (K) + 2) & 15) << 8) + lane * 4); \
        const float hn = chain_step(hl, c, r2, Ui, Uf, Ug, Uo, zcur, real); \
        h_lds[((t0 + (K)) << 6) + lane] = hn; \
        zcur = zn1; zn1 = zn2; }

#pragma unroll 1
    for (int gi = 0; gi < 32; ++gi) {
        const int t0 = gi * 8;
        const int sb = (gi & 1) * 8;
        STEP(0) STEP(1) STEP(2) STEP(3) STEP(4) STEP(5)
        if (gi < 30) {
            STAGE(gi + 2)
            asm volatile("s_waitcnt vmcnt(8)" ::: "memory");
        } else if (gi == 30) {
            asm volatile("s_waitcnt vmcnt(0)" ::: "memory");   // group 31 resident
        }
        STEP(6) STEP(7)
    }
#undef STEP
#undef STAGE

    // all h writes drained before phase-2 reads (same wave; belt-and-braces)
    asm volatile("s_waitcnt lgkmcnt(0)" ::: "memory");
    __builtin_amdgcn_sched_barrier(0);

    // Phase 2: y[p] = sum over my t-slice {t = 8*tb + j} of sum_u h[t][u]*W10[t*6+u][p]
    float yl[10];
#pragma unroll
    for (int p = 0; p < 10; ++p) yl[p] = 0.0f;

#pragma unroll 2
    for (int tb = 0; tb < 32; ++tb) {
        const int t = tb * 8 + j;                       // lanes cover t=0..255 exactly
        const float* hb = h_lds + (t << 6) + (grp << 3);
        const float2 h01 = *(const float2*)(hb + 0);
        const float2 h23 = *(const float2*)(hb + 2);
        const float2 h45 = *(const float2*)(hb + 4);
        const float* wr = W10 + (size_t)t * 60;         // 6 rows x 10
#define ACCU(U, HV) { \
        const float2 w0 = *(const float2*)(wr + (U) * 10 + 0); \
        const float2 w1 = *(const float2*)(wr + (U) * 10 + 2); \
        const float2 w2 = *(const float2*)(wr + (U) * 10 + 4); \
        const float2 w3 = *(const float2*)(wr + (U) * 10 + 6); \
        const float2 w4 = *(const float2*)(wr + (U) * 10 + 8); \
        yl[0] = fmaf(HV, w0.x, yl[0]); yl[1] = fmaf(HV, w0.y, yl[1]); \
        yl[2] = fmaf(HV, w1.x, yl[2]); yl[3] = fmaf(HV, w1.y, yl[3]); \
        yl[4] = fmaf(HV, w2.x, yl[4]); yl[5] = fmaf(HV, w2.y, yl[5]); \
        yl[6] = fmaf(HV, w3.x, yl[6]); yl[7] = fmaf(HV, w3.y, yl[7]); \
        yl[8] = fmaf(HV, w4.x, yl[8]); yl[9] = fmaf(HV, w4.y, yl[9]); }
        ACCU(0, h01.x) ACCU(1, h01.y) ACCU(2, h23.x)
        ACCU(3, h23.y) ACCU(4, h45.x) ACCU(5, h45.y)
#undef ACCU
    }

    // reduce yl across the 8-lane group (each lane had a t-slice partial)
#pragma unroll
    for (int p = 0; p < 10; ++p) {
        float v = yl[p];
        v += dppf<DPP_XOR1>(v);
        v += dppf<DPP_XOR2>(v);
        v += dpp_xor4(v);
        yl[p] = v;
    }

    float o8 = bo[j];
#pragma unroll
    for (int p = 0; p < 10; ++p) o8 = fmaf(yl[p] + b10[p], Wo[p * 8 + j], o8);
    out[(size_t)b * 8 + j] = o8;
}

extern "C" void kernel_launch(void* const* d_in, const int* in_sizes, int n_in,
                              void* d_out, int out_size, void* d_ws, size_t ws_size,
                              hipStream_t stream) {
    const float* x   = (const float*)d_in[0];
    const float* Wa  = (const float*)d_in[1];
    const float* ba  = (const float*)d_in[2];
    const float* Wl  = (const float*)d_in[3];
    const float* Ul  = (const float*)d_in[4];
    const float* bl  = (const float*)d_in[5];
    const float* W10 = (const float*)d_in[6];
    const float* b10 = (const float*)d_in[7];
    const float* Wo  = (const float*)d_in[8];
    const float* bo  = (const float*)d_in[9];
    float* out = (float*)d_out;
    float* xz  = (float*)d_ws;   // BB*TT*24*4 = 96 MiB

    hipLaunchKernelGGL(k_attn_xz, dim3(BB * TT * 4 / 256), dim3(256), 0, stream,
                       x, Wa, ba, Wl, bl, xz);
    hipLaunchKernelGGL(k_scan, dim3(BB / 8), dim3(64), 0, stream,
                       xz, Ul, W10, b10, Wo, bo, out);
}